// Round 2
// baseline (401.327 us; speedup 1.0000x reference)
//
#include <hip/hip_runtime.h>

// ArcFace loss, MI355X. B=512, D=512, C=64000, s=64, m=0.5.
// R9 = R8's persistent-block pipeline, spill-proofed. R8 regressed (263us
// gemm) because the register-staged W pipeline spilled: WRITE_SIZE=174MB
// scratch, VGPR stuck at 128. R9: hand-unrolled 16 k-steps (all stage
// indices are literal tokens), in-flight staging capped at 3 row-pairs
// (48 VGPR), and amdgpu_waves_per_eu(2,2) so the allocator may use up to
// 256 VGPRs (LDS already pins occupancy at 1 block/CU = 2 waves/EU).
// Pipeline: issue next-tile W pairs at k=0,2,4,6 (nt loads), normalize +
// ds_write to sW[nxt] at k=4,6,8,10. One barrier per tile.

#define B_N 512
#define D_N 512
#define C_N 64000
#define S_SCALE 64.0f
#define MARGIN 0.5f
#define EPS_C 1e-7f
#define NREP 16
#define TPB 4          // 64-class tiles per block
#define GRID_GEMM 250  // 250 * 4 * 64 = 64000 classes

typedef unsigned short ushort_t;
typedef __attribute__((ext_vector_type(8))) short short8;   // 8 bf16 (4 VGPRs)
typedef __attribute__((ext_vector_type(4))) float floatx4;  // MFMA acc
typedef __attribute__((ext_vector_type(4))) float fvec4;    // nt loads

__device__ __forceinline__ ushort_t f2bf(float f) {
    unsigned int u = __float_as_uint(f);
    u += 0x7fffu + ((u >> 16) & 1u);  // round-to-nearest-even
    return (ushort_t)(u >> 16);
}

// Normalize x rows -> bf16 in fragment-linear layout:
//   xnT element addr = (kc*512 + row)*8 + j,  kc = k/8 in [0,64), j = k%8.
// Blocks 0..127: 4 rows each. Block 128: zero rowsum replicas.
__global__ void xprep_kernel(const float* __restrict__ x,
                             ushort_t* __restrict__ xnT,
                             float* __restrict__ rowsumR) {
    int b = blockIdx.x;
    int t = threadIdx.x;
    if (b == 128) {
#pragma unroll
        for (int i = 0; i < NREP * B_N / 256; ++i)
            rowsumR[i * 256 + t] = 0.0f;
        return;
    }
    int row  = b * 4 + (t >> 6);
    int lane = t & 63;
    const float4* p = (const float4*)(x + (size_t)row * D_N);
    float4 v0 = p[lane * 2];        // elems [lane*8 .. lane*8+3]
    float4 v1 = p[lane * 2 + 1];    // elems [lane*8+4 .. lane*8+7]
    float ss = v0.x*v0.x + v0.y*v0.y + v0.z*v0.z + v0.w*v0.w
             + v1.x*v1.x + v1.y*v1.y + v1.z*v1.z + v1.w*v1.w;
#pragma unroll
    for (int off = 32; off > 0; off >>= 1) ss += __shfl_xor(ss, off);
    float sc = 1.0f / fmaxf(sqrtf(ss), 1e-12f);
    uint4 o;
    o.x = (unsigned)f2bf(v0.x*sc) | ((unsigned)f2bf(v0.y*sc) << 16);
    o.y = (unsigned)f2bf(v0.z*sc) | ((unsigned)f2bf(v0.w*sc) << 16);
    o.z = (unsigned)f2bf(v1.x*sc) | ((unsigned)f2bf(v1.y*sc) << 16);
    o.w = (unsigned)f2bf(v1.z*sc) | ((unsigned)f2bf(v1.w*sc) << 16);
    *((uint4*)(xnT + ((size_t)(lane << 9) + row) * 8)) = o;
}

// Persistent block: 4 tiles x (64 classes x 512 rows). 8 waves; wave w owns
// rows [w*64, w*64+64) x tile cols [0,64) as 4x4 mfma_f32_16x16x32_bf16.
// sW (XOR swizzle): addr = kc*512 + (row^(kc&7))*8 + k&7, 0 conflicts.
__global__ __launch_bounds__(512)
__attribute__((amdgpu_waves_per_eu(2, 2)))
void gemm_fused_kernel(const float* __restrict__ W,
                       const ushort_t* __restrict__ xnT,
                       const int* __restrict__ y,
                       float* __restrict__ rowsumR,
                       float* __restrict__ tgt) {
    __shared__ ushort_t sW[2][64 * 512];  // 128 KB double-buffered B operand

    int t     = threadIdx.x;
    int lane  = t & 63;
    int w     = t >> 6;     // wave 0..7
    int lq    = lane >> 4;  // quad
    int lc    = lane & 15;
    int cbase = blockIdx.x * (TPB * 64);

    // A-frag pointers into fragment-linear xnT (same for every tile).
    const ushort_t* apT[4];
#pragma unroll
    for (int tm = 0; tm < 4; tm++)
        apT[tm] = xnT + ((size_t)lq * 512 + w * 64 + tm * 16 + lc) * 8;

    float esum[4][4];
#pragma unroll
    for (int tm = 0; tm < 4; tm++)
#pragma unroll
        for (int r = 0; r < 4; r++) esum[tm][r] = 0.0f;

    // ---- prologue: stage + normalize tile 0 into sW[0] ----
#pragma unroll
    for (int rr = 0; rr < 8; ++rr) {
        int row = w * 8 + rr;
        const fvec4* p = (const fvec4*)(W + (size_t)(cbase + row) * D_N);
        fvec4 a = __builtin_nontemporal_load(p + lane * 2);
        fvec4 b = __builtin_nontemporal_load(p + lane * 2 + 1);
        float ss = a.x*a.x + a.y*a.y + a.z*a.z + a.w*a.w
                 + b.x*b.x + b.y*b.y + b.z*b.z + b.w*b.w;
#pragma unroll
        for (int off = 32; off > 0; off >>= 1) ss += __shfl_xor(ss, off);
        float sc = 1.0f / fmaxf(sqrtf(ss), 1e-12f);
        uint4 o;
        o.x = (unsigned)f2bf(a.x*sc) | ((unsigned)f2bf(a.y*sc) << 16);
        o.y = (unsigned)f2bf(a.z*sc) | ((unsigned)f2bf(a.w*sc) << 16);
        o.z = (unsigned)f2bf(b.x*sc) | ((unsigned)f2bf(b.y*sc) << 16);
        o.w = (unsigned)f2bf(b.z*sc) | ((unsigned)f2bf(b.w*sc) << 16);
        int kc = lane;
        int rs = row ^ (kc & 7);
        *((uint4*)(&sW[0][kc * 512 + rs * 8])) = o;
    }
    __syncthreads();

    const ushort_t* sWc = &sW[0][0];
    ushort_t*       sWn = &sW[1][0];

#pragma unroll 1
    for (int tt = 0; tt < TPB; ++tt) {
        const int  cn0     = cbase + tt * 64;
        const bool notlast = (tt < TPB - 1);
        const int  nb      = cn0 + 64;  // next tile's class base

        floatx4 acc[4][4];
#pragma unroll
        for (int i = 0; i < 4; i++)
#pragma unroll
            for (int j = 0; j < 4; j++) acc[i][j] = (floatx4){0.f, 0.f, 0.f, 0.f};

        short8 af[4], afn[4];
        fvec4  stA[4][2], stB[4][2];  // all indices below are literals

#pragma unroll
        for (int tm = 0; tm < 4; tm++) af[tm] = *(const short8*)(apT[tm]);

#define AF_PREF(kk) do { \
    _Pragma("unroll") \
    for (int tm = 0; tm < 4; tm++) \
        afn[tm] = *(const short8*)(apT[tm] + (kk) * 16384); \
} while (0)

#define AF_SWAP() do { \
    _Pragma("unroll") \
    for (int tm = 0; tm < 4; tm++) af[tm] = afn[tm]; \
} while (0)

#define ST_ISSUE(j) do { if (notlast) { \
    const fvec4* p0_ = (const fvec4*)(W + (size_t)(nb + w * 8 + (j) * 2) * D_N); \
    const fvec4* p1_ = (const fvec4*)(W + (size_t)(nb + w * 8 + (j) * 2 + 1) * D_N); \
    stA[j][0] = __builtin_nontemporal_load(p0_ + lane * 2); \
    stB[j][0] = __builtin_nontemporal_load(p0_ + lane * 2 + 1); \
    stA[j][1] = __builtin_nontemporal_load(p1_ + lane * 2); \
    stB[j][1] = __builtin_nontemporal_load(p1_ + lane * 2 + 1); \
} } while (0)

#define ST_CONSUME(j) do { if (notlast) { \
    _Pragma("unroll") \
    for (int rx = 0; rx < 2; ++rx) { \
        int row_ = w * 8 + (j) * 2 + rx; \
        fvec4 a = stA[j][rx]; \
        fvec4 b = stB[j][rx]; \
        float ss = a.x*a.x + a.y*a.y + a.z*a.z + a.w*a.w \
                 + b.x*b.x + b.y*b.y + b.z*b.z + b.w*b.w; \
        _Pragma("unroll") \
        for (int off = 32; off > 0; off >>= 1) ss += __shfl_xor(ss, off); \
        float sc = 1.0f / fmaxf(sqrtf(ss), 1e-12f); \
        uint4 o; \
        o.x = (unsigned)f2bf(a.x*sc) | ((unsigned)f2bf(a.y*sc) << 16); \
        o.y = (unsigned)f2bf(a.z*sc) | ((unsigned)f2bf(a.w*sc) << 16); \
        o.z = (unsigned)f2bf(b.x*sc) | ((unsigned)f2bf(b.y*sc) << 16); \
        o.w = (unsigned)f2bf(b.z*sc) | ((unsigned)f2bf(b.w*sc) << 16); \
        int rs_ = row_ ^ (lane & 7); \
        *((uint4*)(&sWn[lane * 512 + rs_ * 8])) = o; \
    } } } while (0)

#define KMFMA(kk) do { \
    const int kc_ = (kk) * 4 + lq; \
    short8 bfr[4]; \
    _Pragma("unroll") \
    for (int tn = 0; tn < 4; tn++) { \
        int rs_ = (tn * 16 + lc) ^ (kc_ & 7); \
        bfr[tn] = *(const short8*)(&sWc[kc_ * 512 + rs_ * 8]); \
    } \
    _Pragma("unroll") \
    for (int tm = 0; tm < 4; tm++) \
        _Pragma("unroll") \
        for (int tn = 0; tn < 4; tn++) \
            acc[tm][tn] = __builtin_amdgcn_mfma_f32_16x16x32_bf16( \
                af[tm], bfr[tn], acc[tm][tn], 0, 0, 0); \
} while (0)

        // 16 hand-unrolled k-steps. Issue pairs at k=0,2,4,6;
        // consume (normalize + ds_write to sWn) at k=4,6,8,10.
        AF_PREF(1);  ST_ISSUE(0); KMFMA(0);                 AF_SWAP();
        AF_PREF(2);               KMFMA(1);                 AF_SWAP();
        AF_PREF(3);  ST_ISSUE(1); KMFMA(2);                 AF_SWAP();
        AF_PREF(4);               KMFMA(3);                 AF_SWAP();
        AF_PREF(5);  ST_ISSUE(2); KMFMA(4);  ST_CONSUME(0); AF_SWAP();
        AF_PREF(6);               KMFMA(5);                 AF_SWAP();
        AF_PREF(7);  ST_ISSUE(3); KMFMA(6);  ST_CONSUME(1); AF_SWAP();
        AF_PREF(8);               KMFMA(7);                 AF_SWAP();
        AF_PREF(9);               KMFMA(8);  ST_CONSUME(2); AF_SWAP();
        AF_PREF(10);              KMFMA(9);                 AF_SWAP();
        AF_PREF(11);              KMFMA(10); ST_CONSUME(3); AF_SWAP();
        AF_PREF(12);              KMFMA(11);                AF_SWAP();
        AF_PREF(13);              KMFMA(12);                AF_SWAP();
        AF_PREF(14);              KMFMA(13);                AF_SWAP();
        AF_PREF(15);              KMFMA(14);                AF_SWAP();
                                  KMFMA(15);

#undef AF_PREF
#undef AF_SWAP
#undef ST_ISSUE
#undef ST_CONSUME
#undef KMFMA

        // ---- per-tile epilogue: C/D layout col=lane&15, row=lq*4+reg ----
#pragma unroll
        for (int tm = 0; tm < 4; tm++) {
#pragma unroll
            for (int r = 0; r < 4; r++) {
                int grow = w * 64 + tm * 16 + lq * 4 + r;  // batch row
                int yv   = y[grow];
                float es = 0.0f;
#pragma unroll
                for (int tn = 0; tn < 4; tn++) {
                    int gcol = cn0 + tn * 16 + lc;
                    float theta = acc[tm][tn][r];
                    if (gcol == yv) {
                        tgt[grow] = theta;  // exactly one writer device-wide
                    } else {
                        es += __expf(S_SCALE * theta);
                    }
                }
                esum[tm][r] += es;
            }
        }
        __syncthreads();  // sWn complete + all waves done reading sWc
        const ushort_t* tmp_ = sWc;
        sWc = sWn;
        sWn = (ushort_t*)tmp_;
    }

    // ---- final: reduce esum across 16 lc lanes, 1 atomic per row ----
#pragma unroll
    for (int tm = 0; tm < 4; tm++) {
#pragma unroll
        for (int r = 0; r < 4; r++) {
            float e = esum[tm][r];
#pragma unroll
            for (int off = 1; off < 16; off <<= 1) e += __shfl_xor(e, off);
            if (lc == 0) {
                int grow = w * 64 + tm * 16 + lq * 4 + r;
                atomicAdd(&rowsumR[(blockIdx.x & (NREP - 1)) * B_N + grow], e);
            }
        }
    }
}

__global__ void finalize_kernel(const float* __restrict__ rowsumR,
                                const float* __restrict__ tgt,
                                float* __restrict__ out) {
    __shared__ float red[256];
    int t = threadIdx.x;
    float s = 0.0f;
    for (int r = t; r < B_N; r += 256) {
        float rs = 0.0f;
#pragma unroll
        for (int i = 0; i < NREP; ++i) rs += rowsumR[i * B_N + r];
        float tv = tgt[r];
        tv = fminf(fmaxf(tv, -1.0f + EPS_C), 1.0f - EPS_C);
        float num = S_SCALE * cosf(acosf(tv) + MARGIN);
        float den = expf(num) + rs;
        s += num - logf(den);
    }
    red[t] = s;
    __syncthreads();
    for (int o = 128; o > 0; o >>= 1) {
        if (t < o) red[t] += red[t + o];
        __syncthreads();
    }
    if (t == 0) out[0] = -red[0] / (float)B_N;
}

extern "C" void kernel_launch(void* const* d_in, const int* in_sizes, int n_in,
                              void* d_out, int out_size, void* d_ws, size_t ws_size,
                              hipStream_t stream) {
    const float* x = (const float*)d_in[0];
    const int*   y = (const int*)d_in[1];
    const float* W = (const float*)d_in[2];
    float* out = (float*)d_out;

    char* ws = (char*)d_ws;
    ushort_t* xnT   = (ushort_t*)ws;                    // 512 KB (frag-linear)
    float* rowsumR  = (float*)(ws + 524288);            // 32 KB (16 replicas)
    float* tgt      = rowsumR + NREP * B_N;             // 2 KB

    xprep_kernel<<<129, 256, 0, stream>>>(x, xnT, rowsumR);
    gemm_fused_kernel<<<GRID_GEMM, 512, 0, stream>>>(W, xnT, y, rowsumR, tgt);
    finalize_kernel<<<1, 256, 0, stream>>>(rowsumR, tgt, out);
}

// Round 5
// 385.481 us; speedup vs baseline: 1.0411x; 1.0411x over previous
//
#include <hip/hip_runtime.h>

// ArcFace loss, MI355X. B=512, D=512, C=64000, s=64, m=0.5.
// R12 = R10/R11 resubmitted (two container-level infra failures, not
// kernel verdicts; source audited: no OOB, no divergent barriers, no
// uninitialized consumes). Persistent-block pipeline, spill removed.
// R8/R9 post-mortem: VGPR_Count pinned at 128 (arch half of unified
// file; acc in AGPRs); 64-VGPR staging block -> ~32 regs spilled ->
// 164 MB scratch writes. R10+: ONE row-pair in flight per slot, two
// alternating NAMED register sets (32 VGPRs, no arrays), issue at
// k=0,4,8,12, consume at k=4,8,12,15. Distance-4 ~= 2500 cyc of
// block-level MFMA >> 900 cyc HBM latency; issues cover all 16 k-steps
// so the W stream never idles. Arch demand ~118 < 128 -> no spill.

#define B_N 512
#define D_N 512
#define C_N 64000
#define S_SCALE 64.0f
#define MARGIN 0.5f
#define EPS_C 1e-7f
#define NREP 16
#define TPB 4          // 64-class tiles per block
#define GRID_GEMM 250  // 250 * 4 * 64 = 64000 classes

typedef unsigned short ushort_t;
typedef __attribute__((ext_vector_type(8))) short short8;   // 8 bf16 (4 VGPRs)
typedef __attribute__((ext_vector_type(4))) float floatx4;  // MFMA acc
typedef __attribute__((ext_vector_type(4))) float fvec4;    // nt loads

__device__ __forceinline__ ushort_t f2bf(float f) {
    unsigned int u = __float_as_uint(f);
    u += 0x7fffu + ((u >> 16) & 1u);  // round-to-nearest-even
    return (ushort_t)(u >> 16);
}

// Normalize x rows -> bf16 in fragment-linear layout:
//   xnT element addr = (kc*512 + row)*8 + j,  kc = k/8 in [0,64), j = k%8.
// Blocks 0..127: 4 rows each. Block 128: zero rowsum replicas.
__global__ void xprep_kernel(const float* __restrict__ x,
                             ushort_t* __restrict__ xnT,
                             float* __restrict__ rowsumR) {
    int b = blockIdx.x;
    int t = threadIdx.x;
    if (b == 128) {
#pragma unroll
        for (int i = 0; i < NREP * B_N / 256; ++i)
            rowsumR[i * 256 + t] = 0.0f;
        return;
    }
    int row  = b * 4 + (t >> 6);
    int lane = t & 63;
    const float4* p = (const float4*)(x + (size_t)row * D_N);
    float4 v0 = p[lane * 2];        // elems [lane*8 .. lane*8+3]
    float4 v1 = p[lane * 2 + 1];    // elems [lane*8+4 .. lane*8+7]
    float ss = v0.x*v0.x + v0.y*v0.y + v0.z*v0.z + v0.w*v0.w
             + v1.x*v1.x + v1.y*v1.y + v1.z*v1.z + v1.w*v1.w;
#pragma unroll
    for (int off = 32; off > 0; off >>= 1) ss += __shfl_xor(ss, off);
    float sc = 1.0f / fmaxf(sqrtf(ss), 1e-12f);
    uint4 o;
    o.x = (unsigned)f2bf(v0.x*sc) | ((unsigned)f2bf(v0.y*sc) << 16);
    o.y = (unsigned)f2bf(v0.z*sc) | ((unsigned)f2bf(v0.w*sc) << 16);
    o.z = (unsigned)f2bf(v1.x*sc) | ((unsigned)f2bf(v1.y*sc) << 16);
    o.w = (unsigned)f2bf(v1.z*sc) | ((unsigned)f2bf(v1.w*sc) << 16);
    *((uint4*)(xnT + ((size_t)(lane << 9) + row) * 8)) = o;
}

// Persistent block: 4 tiles x (64 classes x 512 rows). 8 waves; wave w owns
// rows [w*64, w*64+64) x tile cols [0,64) as 4x4 mfma_f32_16x16x32_bf16.
// sW (XOR swizzle): addr = kc*512 + (row^(kc&7))*8 + k&7, 0 conflicts.
__global__ __launch_bounds__(512)
__attribute__((amdgpu_waves_per_eu(2, 2)))
void gemm_fused_kernel(const float* __restrict__ W,
                       const ushort_t* __restrict__ xnT,
                       const int* __restrict__ y,
                       float* __restrict__ rowsumR,
                       float* __restrict__ tgt) {
    __shared__ ushort_t sW[2][64 * 512];  // 128 KB double-buffered B operand

    int t     = threadIdx.x;
    int lane  = t & 63;
    int w     = t >> 6;     // wave 0..7
    int lq    = lane >> 4;  // quad
    int lc    = lane & 15;
    int cbase = blockIdx.x * (TPB * 64);

    // A-frag pointers into fragment-linear xnT (same for every tile).
    const ushort_t* apT[4];
#pragma unroll
    for (int tm = 0; tm < 4; tm++)
        apT[tm] = xnT + ((size_t)lq * 512 + w * 64 + tm * 16 + lc) * 8;

    float esum[4][4];
#pragma unroll
    for (int tm = 0; tm < 4; tm++)
#pragma unroll
        for (int r = 0; r < 4; r++) esum[tm][r] = 0.0f;

    // ---- prologue: stage + normalize tile 0 into sW[0] ----
#pragma unroll
    for (int rr = 0; rr < 8; ++rr) {
        int row = w * 8 + rr;
        const fvec4* p = (const fvec4*)(W + (size_t)(cbase + row) * D_N);
        fvec4 a = __builtin_nontemporal_load(p + lane * 2);
        fvec4 b = __builtin_nontemporal_load(p + lane * 2 + 1);
        float ss = a.x*a.x + a.y*a.y + a.z*a.z + a.w*a.w
                 + b.x*b.x + b.y*b.y + b.z*b.z + b.w*b.w;
#pragma unroll
        for (int off = 32; off > 0; off >>= 1) ss += __shfl_xor(ss, off);
        float sc = 1.0f / fmaxf(sqrtf(ss), 1e-12f);
        uint4 o;
        o.x = (unsigned)f2bf(a.x*sc) | ((unsigned)f2bf(a.y*sc) << 16);
        o.y = (unsigned)f2bf(a.z*sc) | ((unsigned)f2bf(a.w*sc) << 16);
        o.z = (unsigned)f2bf(b.x*sc) | ((unsigned)f2bf(b.y*sc) << 16);
        o.w = (unsigned)f2bf(b.z*sc) | ((unsigned)f2bf(b.w*sc) << 16);
        int kc = lane;
        int rs = row ^ (kc & 7);
        *((uint4*)(&sW[0][kc * 512 + rs * 8])) = o;
    }
    __syncthreads();

    const ushort_t* sWc = &sW[0][0];
    ushort_t*       sWn = &sW[1][0];

#pragma unroll 1
    for (int tt = 0; tt < TPB; ++tt) {
        const int  cn0     = cbase + tt * 64;
        const bool notlast = (tt < TPB - 1);
        const int  nb      = cn0 + 64;  // next tile's class base

        floatx4 acc[4][4];
#pragma unroll
        for (int i = 0; i < 4; i++)
#pragma unroll
            for (int j = 0; j < 4; j++) acc[i][j] = (floatx4){0.f, 0.f, 0.f, 0.f};

        short8 af[4], afn[4];
        // Two alternating staging sets, plain named regs (16 VGPR each).
        fvec4 s0r0lo, s0r0hi, s0r1lo, s0r1hi;
        fvec4 s1r0lo, s1r0hi, s1r1lo, s1r1hi;

#pragma unroll
        for (int tm = 0; tm < 4; tm++) af[tm] = *(const short8*)(apT[tm]);

#define AF_PREF(kk) do { \
    _Pragma("unroll") \
    for (int tm = 0; tm < 4; tm++) \
        afn[tm] = *(const short8*)(apT[tm] + (kk) * 16384); \
} while (0)

#define AF_SWAP() do { \
    _Pragma("unroll") \
    for (int tm = 0; tm < 4; tm++) af[tm] = afn[tm]; \
} while (0)

// Issue pair j (rows w*8+2j, w*8+2j+1) into set S.
#define ST_ISSUE(j, S) do { if (notlast) { \
    const fvec4* p0_ = (const fvec4*)(W + (size_t)(nb + w * 8 + (j) * 2) * D_N); \
    const fvec4* p1_ = (const fvec4*)(W + (size_t)(nb + w * 8 + (j) * 2 + 1) * D_N); \
    s##S##r0lo = __builtin_nontemporal_load(p0_ + lane * 2); \
    s##S##r0hi = __builtin_nontemporal_load(p0_ + lane * 2 + 1); \
    s##S##r1lo = __builtin_nontemporal_load(p1_ + lane * 2); \
    s##S##r1hi = __builtin_nontemporal_load(p1_ + lane * 2 + 1); \
} } while (0)

// Normalize one row from (LO,HI) regs and ds_write into sWn.
#define ST_ROW(row_, LO, HI) do { \
    fvec4 a = (LO); \
    fvec4 b = (HI); \
    float ss = a.x*a.x + a.y*a.y + a.z*a.z + a.w*a.w \
             + b.x*b.x + b.y*b.y + b.z*b.z + b.w*b.w; \
    _Pragma("unroll") \
    for (int off = 32; off > 0; off >>= 1) ss += __shfl_xor(ss, off); \
    float sc = 1.0f / fmaxf(sqrtf(ss), 1e-12f); \
    uint4 o; \
    o.x = (unsigned)f2bf(a.x*sc) | ((unsigned)f2bf(a.y*sc) << 16); \
    o.y = (unsigned)f2bf(a.z*sc) | ((unsigned)f2bf(a.w*sc) << 16); \
    o.z = (unsigned)f2bf(b.x*sc) | ((unsigned)f2bf(b.y*sc) << 16); \
    o.w = (unsigned)f2bf(b.z*sc) | ((unsigned)f2bf(b.w*sc) << 16); \
    int rs_ = (row_) ^ (lane & 7); \
    *((uint4*)(&sWn[lane * 512 + rs_ * 8])) = o; \
} while (0)

#define ST_CONSUME(j, S) do { if (notlast) { \
    ST_ROW(w * 8 + (j) * 2,     s##S##r0lo, s##S##r0hi); \
    ST_ROW(w * 8 + (j) * 2 + 1, s##S##r1lo, s##S##r1hi); \
} } while (0)

#define KMFMA(kk) do { \
    const int kc_ = (kk) * 4 + lq; \
    short8 bfr[4]; \
    _Pragma("unroll") \
    for (int tn = 0; tn < 4; tn++) { \
        int rs_ = (tn * 16 + lc) ^ (kc_ & 7); \
        bfr[tn] = *(const short8*)(&sWc[kc_ * 512 + rs_ * 8]); \
    } \
    _Pragma("unroll") \
    for (int tm = 0; tm < 4; tm++) \
        _Pragma("unroll") \
        for (int tn = 0; tn < 4; tn++) \
            acc[tm][tn] = __builtin_amdgcn_mfma_f32_16x16x32_bf16( \
                af[tm], bfr[tn], acc[tm][tn], 0, 0, 0); \
} while (0)

        // 16 hand-unrolled k-steps.
        // Issue pair j at k=4j (sets 0,1,0,1); consume at k=4,8,12,15.
        // Consume precedes the same-step issue, so <=2 sets (32 VGPR) live.
        AF_PREF(1);  ST_ISSUE(0, 0);                  KMFMA(0);  AF_SWAP();
        AF_PREF(2);                                   KMFMA(1);  AF_SWAP();
        AF_PREF(3);                                   KMFMA(2);  AF_SWAP();
        AF_PREF(4);                                   KMFMA(3);  AF_SWAP();
        AF_PREF(5);  ST_CONSUME(0, 0); ST_ISSUE(1, 1); KMFMA(4);  AF_SWAP();
        AF_PREF(6);                                   KMFMA(5);  AF_SWAP();
        AF_PREF(7);                                   KMFMA(6);  AF_SWAP();
        AF_PREF(8);                                   KMFMA(7);  AF_SWAP();
        AF_PREF(9);  ST_CONSUME(1, 1); ST_ISSUE(2, 0); KMFMA(8);  AF_SWAP();
        AF_PREF(10);                                  KMFMA(9);  AF_SWAP();
        AF_PREF(11);                                  KMFMA(10); AF_SWAP();
        AF_PREF(12);                                  KMFMA(11); AF_SWAP();
        AF_PREF(13); ST_CONSUME(2, 0); ST_ISSUE(3, 1); KMFMA(12); AF_SWAP();
        AF_PREF(14);                                  KMFMA(13); AF_SWAP();
        AF_PREF(15);                                  KMFMA(14); AF_SWAP();
                     ST_CONSUME(3, 1);                KMFMA(15);

#undef AF_PREF
#undef AF_SWAP
#undef ST_ISSUE
#undef ST_ROW
#undef ST_CONSUME
#undef KMFMA

        // ---- per-tile epilogue: C/D layout col=lane&15, row=lq*4+reg ----
#pragma unroll
        for (int tm = 0; tm < 4; tm++) {
#pragma unroll
            for (int r = 0; r < 4; r++) {
                int grow = w * 64 + tm * 16 + lq * 4 + r;  // batch row
                int yv   = y[grow];
                float es = 0.0f;
#pragma unroll
                for (int tn = 0; tn < 4; tn++) {
                    int gcol = cn0 + tn * 16 + lc;
                    float theta = acc[tm][tn][r];
                    if (gcol == yv) {
                        tgt[grow] = theta;  // exactly one writer device-wide
                    } else {
                        es += __expf(S_SCALE * theta);
                    }
                }
                esum[tm][r] += es;
            }
        }
        __syncthreads();  // sWn complete + all waves done reading sWc
        const ushort_t* tmp_ = sWc;
        sWc = sWn;
        sWn = (ushort_t*)tmp_;
    }

    // ---- final: reduce esum across 16 lc lanes, 1 atomic per row ----
#pragma unroll
    for (int tm = 0; tm < 4; tm++) {
#pragma unroll
        for (int r = 0; r < 4; r++) {
            float e = esum[tm][r];
#pragma unroll
            for (int off = 1; off < 16; off <<= 1) e += __shfl_xor(e, off);
            if (lc == 0) {
                int grow = w * 64 + tm * 16 + lq * 4 + r;
                atomicAdd(&rowsumR[(blockIdx.x & (NREP - 1)) * B_N + grow], e);
            }
        }
    }
}

__global__ void finalize_kernel(const float* __restrict__ rowsumR,
                                const float* __restrict__ tgt,
                                float* __restrict__ out) {
    __shared__ float red[256];
    int t = threadIdx.x;
    float s = 0.0f;
    for (int r = t; r < B_N; r += 256) {
        float rs = 0.0f;
#pragma unroll
        for (int i = 0; i < NREP; ++i) rs += rowsumR[i * B_N + r];
        float tv = tgt[r];
        tv = fminf(fmaxf(tv, -1.0f + EPS_C), 1.0f - EPS_C);
        float num = S_SCALE * cosf(acosf(tv) + MARGIN);
        float den = expf(num) + rs;
        s += num - logf(den);
    }
    red[t] = s;
    __syncthreads();
    for (int o = 128; o > 0; o >>= 1) {
        if (t < o) red[t] += red[t + o];
        __syncthreads();
    }
    if (t == 0) out[0] = -red[0] / (float)B_N;
}

extern "C" void kernel_launch(void* const* d_in, const int* in_sizes, int n_in,
                              void* d_out, int out_size, void* d_ws, size_t ws_size,
                              hipStream_t stream) {
    const float* x = (const float*)d_in[0];
    const int*   y = (const int*)d_in[1];
    const float* W = (const float*)d_in[2];
    float* out = (float*)d_out;

    char* ws = (char*)d_ws;
    ushort_t* xnT   = (ushort_t*)ws;                    // 512 KB (frag-linear)
    float* rowsumR  = (float*)(ws + 524288);            // 32 KB (16 replicas)
    float* tgt      = rowsumR + NREP * B_N;             // 2 KB

    xprep_kernel<<<129, 256, 0, stream>>>(x, xnT, rowsumR);
    gemm_fused_kernel<<<GRID_GEMM, 512, 0, stream>>>(W, xnT, y, rowsumR, tgt);
    finalize_kernel<<<1, 256, 0, stream>>>(rowsumR, tgt, out);
}

// Round 6
// 384.206 us; speedup vs baseline: 1.0446x; 1.0033x over previous
//
#include <hip/hip_runtime.h>

// ArcFace loss, MI355X. B=512, D=512, C=64000, s=64, m=0.5.
// R13 = persistent pipeline, register demand cut to fit the OBSERVED
// 128-total-VGPR budget (R8/R9/R12 all spilled 146-174 MB scratch with
// VGPR_Count pinned at 128; acc[4][4]=64 leaves ~64 arch regs).
// Cuts: (1) POSTPONED NORM: stage raw bf16(w), theta = dot/||w|| in
// epilogue via norms2[] LDS (kills rsqrt+rescale chain + long a,b live
// ranges); (2) esum regs -> per-tile atomics (-16); (3) afn prefetch
// dropped, af reloaded into dead regs after each KMFMA (-16); staging =
// 1 row/slot, 3 rotating named sets (24 regs peak), distance >=3 steps.
// Steady demand ~118 <= 128 -> no spill even at the harsh budget.

#define B_N 512
#define D_N 512
#define C_N 64000
#define S_SCALE 64.0f
#define MARGIN 0.5f
#define EPS_C 1e-7f
#define NREP 16
#define TPB 4          // 64-class tiles per block
#define GRID_GEMM 250  // 250 * 4 * 64 = 64000 classes

typedef unsigned short ushort_t;
typedef __attribute__((ext_vector_type(8))) short short8;   // 8 bf16 (4 VGPRs)
typedef __attribute__((ext_vector_type(4))) float floatx4;  // MFMA acc
typedef __attribute__((ext_vector_type(4))) float fvec4;    // nt loads

__device__ __forceinline__ ushort_t f2bf(float f) {
    unsigned int u = __float_as_uint(f);
    u += 0x7fffu + ((u >> 16) & 1u);  // round-to-nearest-even
    return (ushort_t)(u >> 16);
}

// Normalize x rows -> bf16 in fragment-linear layout:
//   xnT element addr = (kc*512 + row)*8 + j,  kc = k/8 in [0,64), j = k%8.
// Blocks 0..127: 4 rows each. Block 128: zero rowsum replicas.
__global__ void xprep_kernel(const float* __restrict__ x,
                             ushort_t* __restrict__ xnT,
                             float* __restrict__ rowsumR) {
    int b = blockIdx.x;
    int t = threadIdx.x;
    if (b == 128) {
#pragma unroll
        for (int i = 0; i < NREP * B_N / 256; ++i)
            rowsumR[i * 256 + t] = 0.0f;
        return;
    }
    int row  = b * 4 + (t >> 6);
    int lane = t & 63;
    const float4* p = (const float4*)(x + (size_t)row * D_N);
    float4 v0 = p[lane * 2];        // elems [lane*8 .. lane*8+3]
    float4 v1 = p[lane * 2 + 1];    // elems [lane*8+4 .. lane*8+7]
    float ss = v0.x*v0.x + v0.y*v0.y + v0.z*v0.z + v0.w*v0.w
             + v1.x*v1.x + v1.y*v1.y + v1.z*v1.z + v1.w*v1.w;
#pragma unroll
    for (int off = 32; off > 0; off >>= 1) ss += __shfl_xor(ss, off);
    float sc = 1.0f / fmaxf(sqrtf(ss), 1e-12f);
    uint4 o;
    o.x = (unsigned)f2bf(v0.x*sc) | ((unsigned)f2bf(v0.y*sc) << 16);
    o.y = (unsigned)f2bf(v0.z*sc) | ((unsigned)f2bf(v0.w*sc) << 16);
    o.z = (unsigned)f2bf(v1.x*sc) | ((unsigned)f2bf(v1.y*sc) << 16);
    o.w = (unsigned)f2bf(v1.z*sc) | ((unsigned)f2bf(v1.w*sc) << 16);
    *((uint4*)(xnT + ((size_t)(lane << 9) + row) * 8)) = o;
}

// Persistent block: 4 tiles x (64 classes x 512 rows). 8 waves; wave w owns
// rows [w*64, w*64+64) x tile cols [0,64) as 4x4 mfma_f32_16x16x32_bf16.
// sW (XOR swizzle): addr = kc*512 + (row^(kc&7))*8 + k&7, 0 conflicts.
// sW holds UNNORMALIZED bf16(w); norms2[buf][row] holds ||w||^2.
__global__ __launch_bounds__(512, 2)
void gemm_fused_kernel(const float* __restrict__ W,
                       const ushort_t* __restrict__ xnT,
                       const int* __restrict__ y,
                       float* __restrict__ rowsumR,
                       float* __restrict__ tgt) {
    __shared__ ushort_t sW[2][64 * 512];   // 128 KB double-buffered B operand
    __shared__ float    norms2[2][64];     // per-class ||w||^2

    int t    = threadIdx.x;
    int lane = t & 63;
    int w    = t >> 6;     // wave 0..7
    int lq   = lane >> 4;  // quad
    int lc   = lane & 15;
    int cbase = blockIdx.x * (TPB * 64);
    int rep   = blockIdx.x & (NREP - 1);

    // Single A base pointer; af[tm] at elem offset k*16384 + tm*128.
    const ushort_t* abase = xnT + ((size_t)lq * 512 + w * 64 + lc) * 8;

    // ---- prologue: stage tile 0 (raw bf16 + norm^2) into buf 0 ----
#pragma unroll
    for (int rr = 0; rr < 8; ++rr) {
        int row = w * 8 + rr;
        const fvec4* p = (const fvec4*)(W + (size_t)(cbase + row) * D_N);
        fvec4 a = __builtin_nontemporal_load(p + lane * 2);
        fvec4 b = __builtin_nontemporal_load(p + lane * 2 + 1);
        float ss = a.x*a.x + a.y*a.y + a.z*a.z + a.w*a.w
                 + b.x*b.x + b.y*b.y + b.z*b.z + b.w*b.w;
#pragma unroll
        for (int off = 32; off > 0; off >>= 1) ss += __shfl_xor(ss, off);
        uint4 o;
        o.x = (unsigned)f2bf(a.x) | ((unsigned)f2bf(a.y) << 16);
        o.y = (unsigned)f2bf(a.z) | ((unsigned)f2bf(a.w) << 16);
        o.z = (unsigned)f2bf(b.x) | ((unsigned)f2bf(b.y) << 16);
        o.w = (unsigned)f2bf(b.z) | ((unsigned)f2bf(b.w) << 16);
        *((uint4*)(&sW[0][lane * 512 + (row ^ (lane & 7)) * 8])) = o;
        if (lane == 0) norms2[0][row] = ss;
    }
    __syncthreads();

    const ushort_t* sWc = &sW[0][0];
    ushort_t*       sWn = &sW[1][0];
    const float*    n2c = &norms2[0][0];
    float*          n2n = &norms2[1][0];

#pragma unroll 1
    for (int tt = 0; tt < TPB; ++tt) {
        const int  cn0     = cbase + tt * 64;
        const bool notlast = (tt < TPB - 1);
        const int  nb      = cn0 + 64;  // next tile's class base

        floatx4 acc[4][4];
#pragma unroll
        for (int i = 0; i < 4; i++)
#pragma unroll
            for (int j = 0; j < 4; j++) acc[i][j] = (floatx4){0.f, 0.f, 0.f, 0.f};

        short8 af[4];
        // Three rotating 1-row staging sets (8 VGPR each, 24 peak).
        fvec4 stAlo, stAhi, stBlo, stBhi, stClo, stChi;

#define AFL(kk) do { \
    _Pragma("unroll") \
    for (int tm = 0; tm < 4; tm++) \
        af[tm] = *(const short8*)(abase + (size_t)(kk) * 16384 + tm * 128); \
} while (0)

// Issue row w*8+j (nt loads; keep xnT L2-resident) into set S.
#define ST_ISSUE(j, S) do { if (notlast) { \
    const fvec4* p_ = (const fvec4*)(W + (size_t)(nb + w * 8 + (j)) * D_N); \
    st##S##lo = __builtin_nontemporal_load(p_ + lane * 2); \
    st##S##hi = __builtin_nontemporal_load(p_ + lane * 2 + 1); \
} } while (0)

// Consume set S: norm^2 reduce (1 live reg), raw bf16 pack, ds_write.
#define ST_CONSUME(j, S) do { if (notlast) { \
    fvec4 a = st##S##lo; \
    fvec4 b = st##S##hi; \
    float ss = a.x*a.x + a.y*a.y + a.z*a.z + a.w*a.w \
             + b.x*b.x + b.y*b.y + b.z*b.z + b.w*b.w; \
    _Pragma("unroll") \
    for (int off = 32; off > 0; off >>= 1) ss += __shfl_xor(ss, off); \
    uint4 o; \
    o.x = (unsigned)f2bf(a.x) | ((unsigned)f2bf(a.y) << 16); \
    o.y = (unsigned)f2bf(a.z) | ((unsigned)f2bf(a.w) << 16); \
    o.z = (unsigned)f2bf(b.x) | ((unsigned)f2bf(b.y) << 16); \
    o.w = (unsigned)f2bf(b.z) | ((unsigned)f2bf(b.w) << 16); \
    int row_ = w * 8 + (j); \
    *((uint4*)(&sWn[lane * 512 + (row_ ^ (lane & 7)) * 8])) = o; \
    if (lane == 0) n2n[row_] = ss; \
} } while (0)

#define KMFMA(kk) do { \
    const int kc_ = (kk) * 4 + lq; \
    short8 bfr[4]; \
    _Pragma("unroll") \
    for (int tn = 0; tn < 4; tn++) { \
        int rs_ = (tn * 16 + lc) ^ (kc_ & 7); \
        bfr[tn] = *(const short8*)(&sWc[kc_ * 512 + rs_ * 8]); \
    } \
    _Pragma("unroll") \
    for (int tm = 0; tm < 4; tm++) \
        _Pragma("unroll") \
        for (int tn = 0; tn < 4; tn++) \
            acc[tm][tn] = __builtin_amdgcn_mfma_f32_16x16x32_bf16( \
                af[tm], bfr[tn], acc[tm][tn], 0, 0, 0); \
} while (0)

        // 16 hand-unrolled k-steps. Issue j at k=0,2,4,6,8,10,10,12;
        // consume at k=4,6,8,10,12,14,14,15 (distance >=3 steps ~ >=900cy).
        // af for step k+1 reloaded into dead regs right after KMFMA(k).
        AFL(0);
        ST_ISSUE(0, A);                      KMFMA(0);  AFL(1);
                                             KMFMA(1);  AFL(2);
        ST_ISSUE(1, B);                      KMFMA(2);  AFL(3);
                                             KMFMA(3);  AFL(4);
        ST_CONSUME(0, A); ST_ISSUE(2, C);    KMFMA(4);  AFL(5);
                                             KMFMA(5);  AFL(6);
        ST_CONSUME(1, B); ST_ISSUE(3, A);    KMFMA(6);  AFL(7);
                                             KMFMA(7);  AFL(8);
        ST_CONSUME(2, C); ST_ISSUE(4, B);    KMFMA(8);  AFL(9);
                                             KMFMA(9);  AFL(10);
        ST_CONSUME(3, A); ST_ISSUE(5, C);
        ST_ISSUE(6, A);                      KMFMA(10); AFL(11);
                                             KMFMA(11); AFL(12);
        ST_CONSUME(4, B); ST_ISSUE(7, B);    KMFMA(12); AFL(13);
                                             KMFMA(13); AFL(14);
        ST_CONSUME(5, C); ST_CONSUME(6, A);  KMFMA(14); AFL(15);
        ST_CONSUME(7, B);                    KMFMA(15);

#undef AFL
#undef ST_ISSUE
#undef ST_CONSUME
#undef KMFMA

        // ---- per-tile epilogue. C/D layout: col=lane&15, row=lq*4+reg.
        // theta = acc / ||w_col||  (postponed normalization).
        float rn[4];
#pragma unroll
        for (int tn = 0; tn < 4; tn++) {
            float n2_ = n2c[tn * 16 + lc];
            rn[tn] = 1.0f / fmaxf(sqrtf(n2_), 1e-12f);
        }
#pragma unroll
        for (int tm = 0; tm < 4; tm++) {
#pragma unroll
            for (int r = 0; r < 4; r++) {
                int grow = w * 64 + tm * 16 + lq * 4 + r;  // batch row
                int yv   = y[grow];
                float es = 0.0f;
#pragma unroll
                for (int tn = 0; tn < 4; tn++) {
                    int gcol = cn0 + tn * 16 + lc;
                    float theta = acc[tm][tn][r] * rn[tn];
                    if (gcol == yv) {
                        tgt[grow] = theta;  // exactly one writer device-wide
                    } else {
                        es += __expf(S_SCALE * theta);
                    }
                }
                // reduce across the 16 lc lanes (masks stay within lq group)
#pragma unroll
                for (int off = 1; off < 16; off <<= 1) es += __shfl_xor(es, off);
                if (lc == 0)
                    atomicAdd(&rowsumR[rep * B_N + grow], es);
            }
        }
        __syncthreads();  // sWn+norms2n complete; all waves done with sWc
        const ushort_t* ts_ = sWc; sWc = sWn; sWn = (ushort_t*)ts_;
        const float*    tn_ = n2c; n2c = n2n; n2n = (float*)tn_;
    }
}

__global__ void finalize_kernel(const float* __restrict__ rowsumR,
                                const float* __restrict__ tgt,
                                float* __restrict__ out) {
    __shared__ float red[256];
    int t = threadIdx.x;
    float s = 0.0f;
    for (int r = t; r < B_N; r += 256) {
        float rs = 0.0f;
#pragma unroll
        for (int i = 0; i < NREP; ++i) rs += rowsumR[i * B_N + r];
        float tv = tgt[r];
        tv = fminf(fmaxf(tv, -1.0f + EPS_C), 1.0f - EPS_C);
        float num = S_SCALE * cosf(acosf(tv) + MARGIN);
        float den = expf(num) + rs;
        s += num - logf(den);
    }
    red[t] = s;
    __syncthreads();
    for (int o = 128; o > 0; o >>= 1) {
        if (t < o) red[t] += red[t + o];
        __syncthreads();
    }
    if (t == 0) out[0] = -red[0] / (float)B_N;
}

extern "C" void kernel_launch(void* const* d_in, const int* in_sizes, int n_in,
                              void* d_out, int out_size, void* d_ws, size_t ws_size,
                              hipStream_t stream) {
    const float* x = (const float*)d_in[0];
    const int*   y = (const int*)d_in[1];
    const float* W = (const float*)d_in[2];
    float* out = (float*)d_out;

    char* ws = (char*)d_ws;
    ushort_t* xnT   = (ushort_t*)ws;                    // 512 KB (frag-linear)
    float* rowsumR  = (float*)(ws + 524288);            // 32 KB (16 replicas)
    float* tgt      = rowsumR + NREP * B_N;             // 2 KB

    xprep_kernel<<<129, 256, 0, stream>>>(x, xnT, rowsumR);
    gemm_fused_kernel<<<GRID_GEMM, 512, 0, stream>>>(W, xnT, y, rowsumR, tgt);
    finalize_kernel<<<1, 256, 0, stream>>>(rowsumR, tgt, out);
}

// Round 7
// 263.925 us; speedup vs baseline: 1.5206x; 1.4557x over previous
//
#include <hip/hip_runtime.h>

// ArcFace loss, MI355X. B=512, D=512, C=64000, s=64, m=0.5.
// R14: abandon in-loop register staging (R8-R13 all spilled a FIXED
// ~146 MB scratch block regardless of named-register demand -> the
// spill is structural to the hand-unrolled pipeline body). Back to the
// known-no-spill R7 shape (phase0 stage -> barrier -> runtime K-loop ->
// epilogue, one tile per block), re-tiled for 4-way block concurrency:
// 256 thr (4 waves), 32-class tiles, grid 2000, 32 KB LDS/block ->
// 4 blocks/CU in naturally staggered phases. The HBM W-stream of some
// blocks overlaps the MFMA K-loop of others -- the overlap R8-R13
// tried to construct explicitly, obtained via occupancy instead.
// Keeps R13's postponed normalization (theta = dot(x_hat,bf16(w))/||w||).

#define B_N 512
#define D_N 512
#define C_N 64000
#define S_SCALE 64.0f
#define MARGIN 0.5f
#define EPS_C 1e-7f
#define NREP 16
#define TILE_C 32          // classes per block
#define GRID_GEMM 2000     // 2000 * 32 = 64000

typedef unsigned short ushort_t;
typedef __attribute__((ext_vector_type(8))) short short8;   // 8 bf16 (4 VGPRs)
typedef __attribute__((ext_vector_type(4))) float floatx4;  // MFMA acc
typedef __attribute__((ext_vector_type(4))) float fvec4;    // nt loads

__device__ __forceinline__ ushort_t f2bf(float f) {
    unsigned int u = __float_as_uint(f);
    u += 0x7fffu + ((u >> 16) & 1u);  // round-to-nearest-even
    return (ushort_t)(u >> 16);
}

// Normalize x rows -> bf16 in fragment-linear layout:
//   xnT element addr = (kc*512 + row)*8 + j,  kc = k/8 in [0,64), j = k%8.
// Blocks 0..127: 4 rows each. Block 128: zero rowsum replicas.
__global__ void xprep_kernel(const float* __restrict__ x,
                             ushort_t* __restrict__ xnT,
                             float* __restrict__ rowsumR) {
    int b = blockIdx.x;
    int t = threadIdx.x;
    if (b == 128) {
#pragma unroll
        for (int i = 0; i < NREP * B_N / 256; ++i)
            rowsumR[i * 256 + t] = 0.0f;
        return;
    }
    int row  = b * 4 + (t >> 6);
    int lane = t & 63;
    const float4* p = (const float4*)(x + (size_t)row * D_N);
    float4 v0 = p[lane * 2];        // elems [lane*8 .. lane*8+3]
    float4 v1 = p[lane * 2 + 1];    // elems [lane*8+4 .. lane*8+7]
    float ss = v0.x*v0.x + v0.y*v0.y + v0.z*v0.z + v0.w*v0.w
             + v1.x*v1.x + v1.y*v1.y + v1.z*v1.z + v1.w*v1.w;
#pragma unroll
    for (int off = 32; off > 0; off >>= 1) ss += __shfl_xor(ss, off);
    float sc = 1.0f / fmaxf(sqrtf(ss), 1e-12f);
    uint4 o;
    o.x = (unsigned)f2bf(v0.x*sc) | ((unsigned)f2bf(v0.y*sc) << 16);
    o.y = (unsigned)f2bf(v0.z*sc) | ((unsigned)f2bf(v0.w*sc) << 16);
    o.z = (unsigned)f2bf(v1.x*sc) | ((unsigned)f2bf(v1.y*sc) << 16);
    o.w = (unsigned)f2bf(v1.z*sc) | ((unsigned)f2bf(v1.w*sc) << 16);
    *((uint4*)(xnT + ((size_t)(lane << 9) + row) * 8)) = o;
}

// One block = 32 classes x all 512 batch rows. 4 waves; wave w owns rows
// [w*128, w*128+128) x cols [0,32) as 8x2 mfma_f32_16x16x32_bf16 frags.
// sW (XOR swizzle): ushort addr = kc*256 + (row^(kc&7))*8 + j, kc 0..63,
// row 0..31 -- raw bf16(w); norms2[row] = ||w||^2 (postponed norm).
__global__ __launch_bounds__(256, 4)
void gemm_fused_kernel(const float* __restrict__ W,
                       const ushort_t* __restrict__ xnT,
                       const int* __restrict__ y,
                       float* __restrict__ rowsumR,
                       float* __restrict__ tgt) {
    __shared__ ushort_t sW[64 * 256];   // 32 KB B operand (raw bf16)
    __shared__ float    norms2[TILE_C]; // per-class ||w||^2

    int t    = threadIdx.x;
    int lane = t & 63;
    int w    = t >> 6;     // wave 0..3
    int lq   = lane >> 4;  // quad
    int lc   = lane & 15;
    int cn0  = blockIdx.x * TILE_C;
    int rep  = blockIdx.x & (NREP - 1);

    // ---- Phase 0: stage this block's 32 W rows (8 per wave), nt loads ----
#pragma unroll
    for (int rr = 0; rr < 8; ++rr) {
        int row = w * 8 + rr;  // 0..31
        const fvec4* p = (const fvec4*)(W + (size_t)(cn0 + row) * D_N);
        fvec4 a = __builtin_nontemporal_load(p + lane * 2);
        fvec4 b = __builtin_nontemporal_load(p + lane * 2 + 1);
        float ss = a.x*a.x + a.y*a.y + a.z*a.z + a.w*a.w
                 + b.x*b.x + b.y*b.y + b.z*b.z + b.w*b.w;
#pragma unroll
        for (int off = 32; off > 0; off >>= 1) ss += __shfl_xor(ss, off);
        uint4 o;
        o.x = (unsigned)f2bf(a.x) | ((unsigned)f2bf(a.y) << 16);
        o.y = (unsigned)f2bf(a.z) | ((unsigned)f2bf(a.w) << 16);
        o.z = (unsigned)f2bf(b.x) | ((unsigned)f2bf(b.y) << 16);
        o.w = (unsigned)f2bf(b.z) | ((unsigned)f2bf(b.w) << 16);
        *((uint4*)(&sW[lane * 256 + (row ^ (lane & 7)) * 8])) = o;
        if (lane == 0) norms2[row] = ss;
    }
    __syncthreads();

    // A-frag base into fragment-linear xnT; af[tm] at +tm*128, step k at
    // +k*16384 elems (k advances 4 kc-chunks of 512 rows x 8 elems).
    const ushort_t* abase = xnT + ((size_t)lq * 512 + (size_t)w * 128 + lc) * 8;

    floatx4 acc[8][2];
#pragma unroll
    for (int i = 0; i < 8; i++)
#pragma unroll
        for (int j = 0; j < 2; j++) acc[i][j] = (floatx4){0.f, 0.f, 0.f, 0.f};

    short8 af[8], afn[8];
#pragma unroll
    for (int tm = 0; tm < 8; tm++)
        af[tm] = *(const short8*)(abase + tm * 128);

    for (int k = 0; k < 16; ++k) {
        if (k < 15) {
#pragma unroll
            for (int tm = 0; tm < 8; tm++)
                afn[tm] = *(const short8*)(abase + (size_t)(k + 1) * 16384 + tm * 128);
        }
        int kc = k * 4 + lq;
        short8 bfr[2];
#pragma unroll
        for (int tn = 0; tn < 2; tn++) {
            int rs = (tn * 16 + lc) ^ (kc & 7);
            bfr[tn] = *(const short8*)(&sW[kc * 256 + rs * 8]);
        }
#pragma unroll
        for (int tm = 0; tm < 8; tm++)
#pragma unroll
            for (int tn = 0; tn < 2; tn++)
                acc[tm][tn] = __builtin_amdgcn_mfma_f32_16x16x32_bf16(
                    af[tm], bfr[tn], acc[tm][tn], 0, 0, 0);
        if (k < 15) {
#pragma unroll
            for (int tm = 0; tm < 8; tm++) af[tm] = afn[tm];
        }
    }

    // ---- Epilogue. C/D layout: col = lane&15, row = lq*4 + reg.
    // theta = acc / ||w_col|| (postponed normalization).
    float rn[2];
#pragma unroll
    for (int tn = 0; tn < 2; tn++)
        rn[tn] = 1.0f / fmaxf(sqrtf(norms2[tn * 16 + lc]), 1e-12f);

#pragma unroll
    for (int tm = 0; tm < 8; tm++) {
#pragma unroll
        for (int r = 0; r < 4; r++) {
            int grow = w * 128 + tm * 16 + lq * 4 + r;  // batch row 0..511
            int yv   = y[grow];
            float es = 0.0f;
#pragma unroll
            for (int tn = 0; tn < 2; tn++) {
                int gcol = cn0 + tn * 16 + lc;
                float theta = acc[tm][tn][r] * rn[tn];
                if (gcol == yv) {
                    tgt[grow] = theta;  // exactly one writer device-wide
                } else {
                    es += __expf(S_SCALE * theta);
                }
            }
            // reduce across the 16 lc lanes (stays within lq group)
#pragma unroll
            for (int off = 1; off < 16; off <<= 1) es += __shfl_xor(es, off);
            if (lc == 0)
                atomicAdd(&rowsumR[rep * B_N + grow], es);
        }
    }
}

__global__ void finalize_kernel(const float* __restrict__ rowsumR,
                                const float* __restrict__ tgt,
                                float* __restrict__ out) {
    __shared__ float red[256];
    int t = threadIdx.x;
    float s = 0.0f;
    for (int r = t; r < B_N; r += 256) {
        float rs = 0.0f;
#pragma unroll
        for (int i = 0; i < NREP; ++i) rs += rowsumR[i * B_N + r];
        float tv = tgt[r];
        tv = fminf(fmaxf(tv, -1.0f + EPS_C), 1.0f - EPS_C);
        float num = S_SCALE * cosf(acosf(tv) + MARGIN);
        float den = expf(num) + rs;
        s += num - logf(den);
    }
    red[t] = s;
    __syncthreads();
    for (int o = 128; o > 0; o >>= 1) {
        if (t < o) red[t] += red[t + o];
        __syncthreads();
    }
    if (t == 0) out[0] = -red[0] / (float)B_N;
}

extern "C" void kernel_launch(void* const* d_in, const int* in_sizes, int n_in,
                              void* d_out, int out_size, void* d_ws, size_t ws_size,
                              hipStream_t stream) {
    const float* x = (const float*)d_in[0];
    const int*   y = (const int*)d_in[1];
    const float* W = (const float*)d_in[2];
    float* out = (float*)d_out;

    char* ws = (char*)d_ws;
    ushort_t* xnT   = (ushort_t*)ws;                    // 512 KB (frag-linear)
    float* rowsumR  = (float*)(ws + 524288);            // 32 KB (16 replicas)
    float* tgt      = rowsumR + NREP * B_N;             // 2 KB

    xprep_kernel<<<129, 256, 0, stream>>>(x, xnT, rowsumR);
    gemm_fused_kernel<<<GRID_GEMM, 256, 0, stream>>>(W, xnT, y, rowsumR, tgt);
    finalize_kernel<<<1, 256, 0, stream>>>(rowsumR, tgt, out);
}